// Round 2
// 1509.168 us; speedup vs baseline: 1.3762x; 1.3762x over previous
//
#include <hip/hip_runtime.h>
#include <cstdint>
#include <cstddef>

// Problem constants
#define S_TOT 160     // B*T snapshots
#define NNODE 1000
#define KPAD  1024    // padded K for transposed bf16 buffers
#define NFEAT 128
#define NH    128
#define NH2   64
#define NH3   32
#define NIDX  100
#define TT    20
#define BB    8

typedef __attribute__((ext_vector_type(8))) short short8;
typedef __attribute__((ext_vector_type(4))) float f32x4;

static __device__ __forceinline__ unsigned short f2bf(float f) {
  union { float f; unsigned u; } v; v.f = f;
  unsigned r = v.u + 0x7FFFu + ((v.u >> 16) & 1u);   // RNE
  return (unsigned short)(r >> 16);
}
static __device__ __forceinline__ float bf2f(unsigned short h) {
  union { unsigned u; float f; } v; v.u = ((unsigned)h) << 16;
  return v.f;
}
static __device__ __forceinline__ float sigmoidf_(float x){ return 1.f/(1.f + __expf(-x)); }
static __device__ __forceinline__ float tanhf_(float x){ float e = __expf(2.f*x); return 1.f - 2.f/(e + 1.f); }
static __device__ __forceinline__ float reluf_(float x){ return x > 0.f ? x : 0.f; }

// ---------------------------------------------------------------------------
// K0: features [s][node][f] f32 -> XbfT [s][f][KPAD] bf16 (node-padded with 0)
// grid (32 node-tiles, 4 f-tiles, 160), 256 threads
__global__ __launch_bounds__(256) void k_transpose(const float* __restrict__ feat,
                                                   unsigned short* __restrict__ XbfT) {
  __shared__ float tile[32][33];
  int n0 = blockIdx.x * 32, f0 = blockIdx.y * 32, s = blockIdx.z;
  int tc = threadIdx.x & 31;   // column (feature on read, node on write)
  int tr = threadIdx.x >> 5;   // 8 rows per pass
  #pragma unroll
  for (int p = 0; p < 4; ++p) {
    int node = n0 + tr + p*8;
    float v = 0.f;
    if (node < NNODE) v = feat[((size_t)s*NNODE + node)*NFEAT + f0 + tc];
    tile[tr + p*8][tc] = v;
  }
  __syncthreads();
  #pragma unroll
  for (int p = 0; p < 4; ++p) {
    int f = f0 + tr + p*8;
    int node = n0 + tc;                 // covers 0..1023, pads get 0
    XbfT[((size_t)s*NFEAT + f)*KPAD + node] = f2bf(tile[tc][tr + p*8]);
  }
}

// K0b: zero the node-pad (1000..1023) of a transposed bf16 buffer with `rows` rows
__global__ __launch_bounds__(256) void k_zero_pad(unsigned short* __restrict__ buf, int rows) {
  int i = blockIdx.x*256 + threadIdx.x;
  if (i < rows*24) {
    int r = i / 24, j = i - r*24;
    buf[(size_t)r*KPAD + 1000 + j] = 0;
  }
}

// ---------------------------------------------------------------------------
// agg: out[s][m][n] = sum_k adj[s][m][k] * B[s][k][n], B given transposed bf16
// A: f32 global -> bf16 LDS (fragment-major). B: direct 16B global fragment loads.
// out: row-major bf16 [160000][128]. grid 2560 (XCD-swizzled), 256 threads.
__global__ __launch_bounds__(256) void k_agg(const float* __restrict__ adj,
                                             const unsigned short* __restrict__ BT,
                                             unsigned short* __restrict__ out) {
  __shared__ short lds[8192];               // 16KB: A-frag region [0,2048), epilogue uses all
  int bid = blockIdx.x;
  int c8 = bid & 7, q = bid >> 3;
  int s  = c8*20 + (q >> 4);                // 16 row-blocks of one snapshot stay on one XCD
  int rb = (q & 15) * 64;
  int t = threadIdx.x, lane = t & 63, w = t >> 6;

  f32x4 acc[4][2];
  #pragma unroll
  for (int i = 0; i < 4; ++i) { acc[i][0] = (f32x4)0.f; acc[i][1] = (f32x4)0.f; }

  const size_t adj_s = (size_t)s*NNODE*NNODE;
  const unsigned short* BTs = BT + (size_t)s*NFEAT*KPAD;

  for (int c = 0; c < 32; ++c) {
    int k0 = c*32;
    // stage A: 64 rows x 32 k, f32 -> bf16, fragment-major
    #pragma unroll
    for (int hlf = 0; hlf < 2; ++hlf) {
      int g = t + hlf*256;                  // 0..511 float4 slots
      int r = g >> 3, c4 = g & 7;
      int row = rb + r, col = k0 + c4*4;
      float4 v = make_float4(0.f,0.f,0.f,0.f);
      if (row < NNODE && col < NNODE)
        v = *(const float4*)(adj + adj_s + (size_t)row*NNODE + col);
      unsigned short b0=f2bf(v.x), b1=f2bf(v.y), b2=f2bf(v.z), b3=f2bf(v.w);
      int mt = r >> 4;
      int l  = (r & 15) | ((c4 >> 1) << 4);
      int off = (mt*64 + l)*8 + (c4 & 1)*4;
      *(uint2*)(&lds[off]) = make_uint2((unsigned)b0 | ((unsigned)b1<<16),
                                        (unsigned)b2 | ((unsigned)b3<<16));
    }
    __syncthreads();
    short8 bfr[2];
    #pragma unroll
    for (int t2 = 0; t2 < 2; ++t2) {
      int n = (w*2 + t2)*16 + (lane & 15);
      bfr[t2] = *(const short8*)(BTs + (size_t)n*KPAD + k0 + (lane >> 4)*8);
    }
    #pragma unroll
    for (int mt = 0; mt < 4; ++mt) {
      short8 afr = *(const short8*)(&lds[(mt*64 + lane)*8]);
      acc[mt][0] = __builtin_amdgcn_mfma_f32_16x16x32_bf16(afr, bfr[0], acc[mt][0], 0, 0, 0);
      acc[mt][1] = __builtin_amdgcn_mfma_f32_16x16x32_bf16(afr, bfr[1], acc[mt][1], 0, 0, 0);
    }
    __syncthreads();
  }
  // epilogue: acc -> LDS [64][128] bf16 -> coalesced row-major stores
  #pragma unroll
  for (int mt = 0; mt < 4; ++mt)
    #pragma unroll
    for (int t2 = 0; t2 < 2; ++t2) {
      int colbase = (w*2 + t2)*16 + (lane & 15);
      int rowbase = mt*16 + (lane >> 4)*4;
      #pragma unroll
      for (int r = 0; r < 4; ++r)
        lds[(rowbase + r)*128 + colbase] = (short)f2bf(acc[mt][t2][r]);
    }
  __syncthreads();
  {
    int row = t >> 2, seg = t & 3;
    int node = rb + row;
    if (node < NNODE) {
      const uint4* src = (const uint4*)(&lds[row*128 + seg*32]);
      uint4* dst = (uint4*)(out + ((size_t)s*NNODE + node)*NH + seg*32);
      dst[0] = src[0]; dst[1] = src[1]; dst[2] = src[2]; dst[3] = src[3];
    }
  }
}

// ---------------------------------------------------------------------------
// layer1: h1 = relu(AX @ Wg1 + bg1), written TRANSPOSED bf16 to h1T [s][f][KPAD]
// grid 2500 (M=160000/64), 256 threads
__global__ __launch_bounds__(256) void k_layer1(const unsigned short* __restrict__ A,
                                                const float* __restrict__ W,
                                                const float* __restrict__ bias,
                                                unsigned short* __restrict__ h1T) {
  int rb = blockIdx.x * 64;
  int t = threadIdx.x, lane = t & 63, w = t >> 6;
  short8 bf[4][2];
  #pragma unroll
  for (int kc = 0; kc < 4; ++kc)
    #pragma unroll
    for (int t2 = 0; t2 < 2; ++t2) {
      int n = (w*2 + t2)*16 + (lane & 15);
      #pragma unroll
      for (int j = 0; j < 8; ++j)
        bf[kc][t2][j] = (short)f2bf(W[(kc*32 + (lane>>4)*8 + j)*NH + n]);
    }
  f32x4 acc[4][2];
  #pragma unroll
  for (int i = 0; i < 4; ++i) { acc[i][0] = (f32x4)0.f; acc[i][1] = (f32x4)0.f; }
  #pragma unroll
  for (int mt = 0; mt < 4; ++mt) {
    int m = rb + mt*16 + (lane & 15);
    const unsigned short* arow = A + (size_t)m*NFEAT + (lane>>4)*8;
    #pragma unroll
    for (int kc = 0; kc < 4; ++kc) {
      short8 af = *(const short8*)(arow + kc*32);
      acc[mt][0] = __builtin_amdgcn_mfma_f32_16x16x32_bf16(af, bf[kc][0], acc[mt][0], 0, 0, 0);
      acc[mt][1] = __builtin_amdgcn_mfma_f32_16x16x32_bf16(af, bf[kc][1], acc[mt][1], 0, 0, 0);
    }
  }
  #pragma unroll
  for (int mt = 0; mt < 4; ++mt)
    #pragma unroll
    for (int t2 = 0; t2 < 2; ++t2) {
      int n = (w*2 + t2)*16 + (lane & 15);
      float bn = bias[n];
      int m0 = rb + mt*16 + (lane>>4)*4;
      int s = m0 / 1000, node = m0 - s*1000;    // 4-row group never straddles a snapshot
      unsigned short pk[4];
      #pragma unroll
      for (int r = 0; r < 4; ++r) pk[r] = f2bf(reluf_(acc[mt][t2][r] + bn));
      *(uint2*)(h1T + ((size_t)s*NH + n)*KPAD + node) =
          make_uint2((unsigned)pk[0] | ((unsigned)pk[1]<<16),
                     (unsigned)pk[2] | ((unsigned)pk[3]<<16));
    }
}

// ---------------------------------------------------------------------------
// layer2: h2 = relu([AH1 | AX] @ Wg2 + bg2), written TRANSPOSED bf16 to h2T [s][f][KPAD]
// grid 2500, 256 threads
__global__ __launch_bounds__(256) void k_layer2(const unsigned short* __restrict__ AH1,
                                                const unsigned short* __restrict__ AX,
                                                const float* __restrict__ W,
                                                const float* __restrict__ bias,
                                                unsigned short* __restrict__ h2T) {
  int rb = blockIdx.x * 64;
  int t = threadIdx.x, lane = t & 63, w = t >> 6;
  int n = w*16 + (lane & 15);
  short8 bf[8];
  #pragma unroll
  for (int kc = 0; kc < 8; ++kc)
    #pragma unroll
    for (int j = 0; j < 8; ++j)
      bf[kc][j] = (short)f2bf(W[(kc*32 + (lane>>4)*8 + j)*NH2 + n]);
  f32x4 acc[4];
  #pragma unroll
  for (int i = 0; i < 4; ++i) acc[i] = (f32x4)0.f;
  #pragma unroll
  for (int mt = 0; mt < 4; ++mt) {
    int m = rb + mt*16 + (lane & 15);
    const unsigned short* a1 = AH1 + (size_t)m*NH   + (lane>>4)*8;
    const unsigned short* a2 = AX  + (size_t)m*NFEAT + (lane>>4)*8;
    #pragma unroll
    for (int kc = 0; kc < 4; ++kc) {
      short8 af = *(const short8*)(a1 + kc*32);
      acc[mt] = __builtin_amdgcn_mfma_f32_16x16x32_bf16(af, bf[kc], acc[mt], 0, 0, 0);
    }
    #pragma unroll
    for (int kc = 0; kc < 4; ++kc) {
      short8 af = *(const short8*)(a2 + kc*32);
      acc[mt] = __builtin_amdgcn_mfma_f32_16x16x32_bf16(af, bf[kc+4], acc[mt], 0, 0, 0);
    }
  }
  float bn = bias[n];
  #pragma unroll
  for (int mt = 0; mt < 4; ++mt) {
    int m0 = rb + mt*16 + (lane>>4)*4;
    int s = m0 / 1000, node = m0 - s*1000;      // 4-row group never straddles a snapshot
    unsigned short pk[4];
    #pragma unroll
    for (int r = 0; r < 4; ++r) pk[r] = f2bf(reluf_(acc[mt][r] + bn));
    *(uint2*)(h2T + ((size_t)s*NH2 + n)*KPAD + node) =
        make_uint2((unsigned)pk[0] | ((unsigned)pk[1]<<16),
                   (unsigned)pk[2] | ((unsigned)pk[3]<<16));
  }
}

// ---------------------------------------------------------------------------
// k_agg_idx: MFMA replacement for old VALU k3a.
// Partial over k-slice p: AH2p[((s*8+p)*NIDX+i)*NH2+f] = sum_{k in [p*128,p*128+128)}
//     bf16(adj[s][idx[i]][k]) * h2T[s][f][k]
// grid (8, 160), 256 threads. M padded 100->112 (7 m-tiles), K-chunking identical to k_agg.
__global__ __launch_bounds__(256) void k_agg_idx(const float* __restrict__ adj,
                                                 const unsigned short* __restrict__ h2T,
                                                 const int* __restrict__ idx,
                                                 float* __restrict__ AH2p) {
  __shared__ float smem[NIDX*NH2];          // 25.6KB; first 7168B doubles as A-frag region
  short* lds = (short*)smem;
  int p = blockIdx.x, s = blockIdx.y;
  int t = threadIdx.x, lane = t & 63, w = t >> 6;

  // gathered node per staging slot (constant across k-chunks)
  int nodes[4];
  #pragma unroll
  for (int hlf = 0; hlf < 4; ++hlf) {
    int g = t + hlf*256, r = g >> 3;
    nodes[hlf] = (g < 896 && r < NIDX) ? idx[r] : -1;
  }

  f32x4 acc[7];
  #pragma unroll
  for (int i = 0; i < 7; ++i) acc[i] = (f32x4)0.f;

  const size_t adj_s = (size_t)s*NNODE*NNODE;
  const unsigned short* BTs = h2T + (size_t)s*NH2*KPAD;

  for (int c = 0; c < 4; ++c) {
    int k0 = p*128 + c*32;
    // stage A: 112 gathered rows x 32 k, f32 -> bf16, fragment-major
    #pragma unroll
    for (int hlf = 0; hlf < 4; ++hlf) {
      int g = t + hlf*256;
      if (g < 896) {
        int r = g >> 3, c4 = g & 7;
        int node = nodes[hlf];
        int col = k0 + c4*4;
        float4 v = make_float4(0.f,0.f,0.f,0.f);
        if (node >= 0 && col < NNODE)
          v = *(const float4*)(adj + adj_s + (size_t)node*NNODE + col);
        unsigned short b0=f2bf(v.x), b1=f2bf(v.y), b2=f2bf(v.z), b3=f2bf(v.w);
        int mt = r >> 4;
        int l  = (r & 15) | ((c4 >> 1) << 4);
        int off = (mt*64 + l)*8 + (c4 & 1)*4;
        *(uint2*)(&lds[off]) = make_uint2((unsigned)b0 | ((unsigned)b1<<16),
                                          (unsigned)b2 | ((unsigned)b3<<16));
      }
    }
    __syncthreads();
    short8 bfr = *(const short8*)(BTs + (size_t)(w*16 + (lane & 15))*KPAD + k0 + (lane >> 4)*8);
    #pragma unroll
    for (int mt = 0; mt < 7; ++mt) {
      short8 afr = *(const short8*)(&lds[(mt*64 + lane)*8]);
      acc[mt] = __builtin_amdgcn_mfma_f32_16x16x32_bf16(afr, bfr, acc[mt], 0, 0, 0);
    }
    __syncthreads();
  }
  // epilogue: acc -> LDS [100][64] f32 -> coalesced stores
  {
    int f = w*16 + (lane & 15);
    #pragma unroll
    for (int mt = 0; mt < 7; ++mt) {
      int rowbase = mt*16 + (lane >> 4)*4;
      #pragma unroll
      for (int r = 0; r < 4; ++r) {
        int row = rowbase + r;
        if (row < NIDX) smem[row*NH2 + f] = acc[mt][r];
      }
    }
  }
  __syncthreads();
  {
    float* dst = AH2p + (((size_t)s*8 + p)*NIDX)*NH2;
    for (int e = t; e < NIDX*16; e += 256) {
      int row = e >> 4, seg = e & 15;
      *(f32x4*)(dst + row*NH2 + seg*4) = *(const f32x4*)(&smem[row*NH2 + seg*4]);
    }
  }
}

// ---------------------------------------------------------------------------
// k3b: reduce AH2p, h3 = relu([AH2|AH1_idx]@Wg3+b), h = relu([h3|h2_idx|h1_idx]@Wgo+b),
//      g[s] = mean_i h.  grid 160, 512 threads.  LDS < 64KB.
__global__ __launch_bounds__(512) void k3b(const float* __restrict__ AH2p,
                                           const unsigned short* __restrict__ AH1,
                                           const unsigned short* __restrict__ h2T,
                                           const unsigned short* __restrict__ h1T,
                                           const float* __restrict__ Wg3, const float* __restrict__ bg3,
                                           const float* __restrict__ Wgo, const float* __restrict__ bgo,
                                           const int* __restrict__ idx,
                                           float* __restrict__ g) {
  __shared__ unsigned short A3[NIDX*192];   // 38.4KB bf16, cols 0..63 then 64..191
  __shared__ float h3s[NIDX*NH3];           // 12.8KB
  __shared__ int idxs[NIDX];
  __shared__ float gpart[4][NH];
  int s = blockIdx.x, t = threadIdx.x;
  if (t < NIDX) idxs[t] = idx[t];
  // AH2 reduce -> A3[:, :64]
  for (int e = t; e < NIDX*64; e += 512) {
    int i = e >> 6, f = e & 63;
    float a = 0.f;
    #pragma unroll
    for (int p = 0; p < 8; ++p)
      a += AH2p[(((size_t)s*8 + p)*NIDX + i)*NH2 + f];
    A3[i*192 + f] = f2bf(a);
  }
  __syncthreads();
  // AH1 gather -> A3[:, 64:192]
  for (int e = t; e < NIDX*128; e += 512) {
    int i = e >> 7, k = e & 127;
    A3[i*192 + 64 + k] = AH1[((size_t)s*NNODE + idxs[i])*NH + k];
  }
  __syncthreads();
  // h3
  for (int o = t; o < NIDX*NH3; o += 512) {
    int i = o >> 5, n = o & 31;
    float a = bg3[n];
    for (int k = 0; k < 192; ++k) a += bf2f(A3[i*192 + k]) * Wg3[k*NH3 + n];
    h3s[o] = reluf_(a);
  }
  __syncthreads();
  // overwrite A3 with [h2_idx | h1_idx]
  for (int e = t; e < NIDX*64; e += 512) {
    int i = e >> 6, f = e & 63;
    A3[i*192 + f] = h2T[((size_t)s*NH2 + f)*KPAD + idxs[i]];
  }
  for (int e = t; e < NIDX*128; e += 512) {
    int i = e >> 7, k = e & 127;
    A3[i*192 + 64 + k] = h1T[((size_t)s*NH + k)*KPAD + idxs[i]];
  }
  __syncthreads();
  // h out + mean readout; Wgo rows: 0..31 h3, 32..95 h2, 96..223 h1
  {
    int n = t & 127, quarter = t >> 7;
    float accg = 0.f;
    for (int grp = 0; grp < 5; ++grp) {
      int ib = quarter*25 + grp*5;
      float a[5];
      #pragma unroll
      for (int r = 0; r < 5; ++r) a[r] = bgo[n];
      for (int k = 0; k < 32; ++k) {
        float wv = Wgo[k*NH + n];
        #pragma unroll
        for (int r = 0; r < 5; ++r) a[r] += h3s[(ib + r)*NH3 + k] * wv;
      }
      for (int k = 0; k < 192; ++k) {
        float wv = Wgo[(32 + k)*NH + n];
        #pragma unroll
        for (int r = 0; r < 5; ++r) a[r] += bf2f(A3[(ib + r)*192 + k]) * wv;
      }
      #pragma unroll
      for (int r = 0; r < 5; ++r) accg += reluf_(a[r]);
    }
    gpart[quarter][n] = accg;
  }
  __syncthreads();
  if (t < NH)
    g[(size_t)s*NH + t] = (gpart[0][t] + gpart[1][t] + gpart[2][t] + gpart[3][t]) * (1.f/NIDX);
}

// ---------------------------------------------------------------------------
// k4a: XW[s][u] = b_ih[u]+b_hh[u] + sum_k g[s][k]*W_ih[u][k]   (t-parallel part)
__global__ __launch_bounds__(256) void k4a(const float* __restrict__ g,
                                           const float* __restrict__ Wih,
                                           const float* __restrict__ bih,
                                           const float* __restrict__ bhh,
                                           float* __restrict__ XW) {
  __shared__ float gv[NH];
  int s = blockIdx.x, t = threadIdx.x;
  if (t < NH) gv[t] = g[(size_t)s*NH + t];
  __syncthreads();
  for (int u = t; u < 512; u += 256) {
    float a = bih[u] + bhh[u];
    const float* wr = Wih + (size_t)u*NH;
    float a0=0.f, a1=0.f;
    for (int k = 0; k < NH; k += 2) { a0 += gv[k]*wr[k]; a1 += gv[k+1]*wr[k+1]; }
    XW[(size_t)s*512 + u] = a + a0 + a1;
  }
}

// k4b: sequential LSTM over T, one block per batch element, 512 threads (1 gate-unit each)
__global__ __launch_bounds__(512) void k4b(const float* __restrict__ XW,
                                           const float* __restrict__ Whh,
                                           const int* __restrict__ lengths,
                                           const float* __restrict__ Wfc,
                                           const float* __restrict__ bfc,
                                           float* __restrict__ out) {
  __shared__ float hb[NH], cb[NH], gates[512], last[NH], red[8];
  int b = blockIdx.x, t = threadIdx.x;
  if (t < NH) { hb[t] = 0.f; cb[t] = 0.f; last[t] = 0.f; }
  int len = lengths[b];
  __syncthreads();
  const float* wr = Whh + (size_t)t*NH;
  for (int step = 0; step < TT; ++step) {
    float a = XW[((size_t)b*TT + step)*512 + t];
    float a0=0.f, a1=0.f, a2=0.f, a3=0.f;
    for (int k = 0; k < NH; k += 4) {
      a0 += hb[k]*wr[k];   a1 += hb[k+1]*wr[k+1];
      a2 += hb[k+2]*wr[k+2]; a3 += hb[k+3]*wr[k+3];
    }
    gates[t] = a + ((a0+a1)+(a2+a3));
    __syncthreads();
    if (t < NH) {
      float ig = sigmoidf_(gates[t]);
      float fg = sigmoidf_(gates[NH + t]);
      float gg = tanhf_(gates[2*NH + t]);
      float og = sigmoidf_(gates[3*NH + t]);
      float c = fg*cb[t] + ig*gg;
      float h = og*tanhf_(c);
      cb[t] = c; hb[t] = h;
      if (step == len - 1) last[t] = h;
    }
    __syncthreads();
  }
  float p = (t < NH) ? last[t]*Wfc[t] : 0.f;
  p += __shfl_down(p, 32, 64); p += __shfl_down(p, 16, 64); p += __shfl_down(p, 8, 64);
  p += __shfl_down(p, 4, 64);  p += __shfl_down(p, 2, 64);  p += __shfl_down(p, 1, 64);
  if ((t & 63) == 0) red[t >> 6] = p;
  __syncthreads();
  if (t == 0) {
    float ssum = 0.f;
    #pragma unroll
    for (int i = 0; i < 8; ++i) ssum += red[i];
    out[b] = ssum + bfc[0];
  }
}

// ---------------------------------------------------------------------------
extern "C" void kernel_launch(void* const* d_in, const int* in_sizes, int n_in,
                              void* d_out, int out_size, void* d_ws, size_t ws_size,
                              hipStream_t stream) {
  const float* adj   = (const float*)d_in[0];
  const float* feat  = (const float*)d_in[1];
  const float* Wg1   = (const float*)d_in[2];
  const float* bg1   = (const float*)d_in[3];
  const float* Wg2   = (const float*)d_in[4];
  const float* bg2   = (const float*)d_in[5];
  const float* Wg3   = (const float*)d_in[6];
  const float* bg3   = (const float*)d_in[7];
  const float* Wgo   = (const float*)d_in[8];
  const float* bgo   = (const float*)d_in[9];
  const float* Wih   = (const float*)d_in[10];
  const float* Whh   = (const float*)d_in[11];
  const float* bih   = (const float*)d_in[12];
  const float* bhh   = (const float*)d_in[13];
  const float* Wfc   = (const float*)d_in[14];
  const float* bfc   = (const float*)d_in[15];
  const int*   idx   = (const int*)d_in[16];
  const int*   lens  = (const int*)d_in[17];
  float* out = (float*)d_out;
  char* ws = (char*)d_ws;

  // Workspace layout (lifetime-aliased), max used = 145,817,600 B (~139 MB)
  const size_t O_XBFT = 0;                      // 41,943,040  (also AH1bf after agg1 done)
  const size_t O_H1T  = 41943040;               // 41,943,040
  const size_t O_AXBF = 83886080;               // 40,960,000  (also AH2p/g/XW after layer2)
  const size_t O_H2T  = 124846080;              // 20,971,520  (h2T bf16 [160][64][1024])
  unsigned short* XbfT  = (unsigned short*)(ws + O_XBFT);
  unsigned short* AH1bf = (unsigned short*)(ws + O_XBFT);     // alias (XbfT dead after agg1)
  unsigned short* h1T   = (unsigned short*)(ws + O_H1T);
  unsigned short* AXbf  = (unsigned short*)(ws + O_AXBF);
  unsigned short* h2T   = (unsigned short*)(ws + O_H2T);
  float* AH2p = (float*)(ws + O_AXBF);                        // alias (AXbf dead after layer2)
  float* g    = (float*)(ws + O_AXBF + 32768000);
  float* XW   = (float*)(ws + O_AXBF + 32768000 + 81920);

  k_transpose   <<<dim3(32, 4, S_TOT), 256, 0, stream>>>(feat, XbfT);
  k_zero_pad    <<<1920, 256, 0, stream>>>(h1T, S_TOT*NH);
  k_zero_pad    <<<960, 256, 0, stream>>>(h2T, S_TOT*NH2);
  k_agg         <<<2560, 256, 0, stream>>>(adj, XbfT, AXbf);          // AX = adj @ x
  k_layer1      <<<2500, 256, 0, stream>>>(AXbf, Wg1, bg1, h1T);      // h1 (transposed)
  k_agg         <<<2560, 256, 0, stream>>>(adj, h1T, AH1bf);          // AH1 = adj @ h1
  k_layer2      <<<2500, 256, 0, stream>>>(AH1bf, AXbf, Wg2, bg2, h2T);// h2 (transposed bf16)
  k_agg_idx     <<<dim3(8, S_TOT), 256, 0, stream>>>(adj, h2T, idx, AH2p);
  k3b           <<<S_TOT, 512, 0, stream>>>(AH2p, AH1bf, h2T, h1T, Wg3, bg3, Wgo, bgo, idx, g);
  k4a           <<<S_TOT, 256, 0, stream>>>(g, Wih, bih, bhh, XW);
  k4b           <<<BB, 512, 0, stream>>>(XW, Whh, lens, Wfc, bfc, out);
}